// Round 1
// baseline (1413.558 us; speedup 1.0000x reference)
//
#include <hip/hip_runtime.h>
#include <hip/hip_bf16.h>
#include <cstdint>

#define BB 4
#define TT 2048
#define DD 1024
#define HH 16
#define NR (BB*TT)   /* 8192 rows */
#define PF 8         /* scan prefetch depth (slots) */

typedef __attribute__((ext_vector_type(8))) short bf16x8;
typedef __attribute__((ext_vector_type(4))) float f32x4;
typedef __attribute__((ext_vector_type(4))) unsigned int u32x4;
typedef __attribute__((ext_vector_type(2))) unsigned int u32x2;

// async global->LDS (CK-style addrspace casts; dest = wave-uniform base + lane*SZ)
#define GLL(g, l, SZ) __builtin_amdgcn_global_load_lds( \
    (const __attribute__((address_space(1))) void*)(uintptr_t)(const void*)(g), \
    (__attribute__((address_space(3))) void*)(uintptr_t)(void*)(l), SZ, 0, 0)

__device__ __forceinline__ unsigned short f2bf(float f) {
  unsigned u = __builtin_bit_cast(unsigned, f);
  unsigned r = 0x7FFFu + ((u >> 16) & 1u);
  return (unsigned short)((u + r) >> 16);
}
__device__ __forceinline__ unsigned pk2(float a, float b) {
  return (unsigned)f2bf(a) | ((unsigned)f2bf(b) << 16);
}
__device__ __forceinline__ float siluf(float v) { return v / (1.f + __expf(-v)); }
__device__ __forceinline__ float sigmf(float v) { return 1.f / (1.f + __expf(-v)); }

// ---------------- weight preprocessing ----------------

// W [K][N] f32 -> Wt [N][K] bf16 (tiled transpose)
__global__ __launch_bounds__(256) void transpose_convert(
    const float* __restrict__ W, unsigned short* __restrict__ Wt, int K, int N) {
  __shared__ float tile[64][65];
  const int tid = threadIdx.x;
  const int bk = blockIdx.x * 64, bn = blockIdx.y * 64;
  const int r = tid >> 2, c4 = (tid & 3) * 16;
#pragma unroll 4
  for (int e = 0; e < 16; ++e)
    tile[r][c4 + e] = W[(size_t)(bk + r) * N + bn + c4 + e];
  __syncthreads();
#pragma unroll 4
  for (int e = 0; e < 16; ++e)
    Wt[(size_t)(bn + r) * K + bk + c4 + e] = f2bf(tile[c4 + e][r]);
}

// W [K][N] f32 -> Wt [Npad][K] bf16, zero rows >= N  (small weights)
__global__ void conv_small_T(const float* __restrict__ W, unsigned short* __restrict__ Wt,
                             int K, int N, int Npad) {
  int idx = blockIdx.x * 256 + threadIdx.x;
  if (idx >= Npad * K) return;
  int n = idx / K, k = idx - n * K;
  float v = (n < N) ? W[(size_t)k * N + n] : 0.f;
  Wt[idx] = f2bf(v);
}

// concat [W_ad | W_gd | W_beta]^T -> Wt [256][1024] bf16 (pad rows 144..255 = 0)
__global__ void pack_stage1_T(const float* __restrict__ Wad, const float* __restrict__ Wgd,
                              const float* __restrict__ Wbeta, unsigned short* __restrict__ Wt) {
  int idx = blockIdx.x * 256 + threadIdx.x;  // over 256*1024
  int n = idx >> 10, k = idx & 1023;
  float v = 0.f;
  if (n < 64) v = Wad[(size_t)k * 64 + n];
  else if (n < 128) v = Wgd[(size_t)k * 64 + (n - 64)];
  else if (n < 144) v = Wbeta[(size_t)k * 16 + (n - 128)];
  Wt[idx] = f2bf(v);
}

__global__ void pack_bias(const float* __restrict__ bad, const float* __restrict__ bgd,
                          const float* __restrict__ bbeta, const float* __restrict__ bgu,
                          float* __restrict__ bst1, float* __restrict__ bgup) {
  int t = threadIdx.x;  // 256
  float v = 0.f;
  if (t < 64) v = bad[t];
  else if (t < 128) v = bgd[t - 64];
  else if (t < 144) v = bbeta[t - 128];
  bst1[t] = v;
  if (t < 128) bgup[t] = (t < 16) ? bgu[t] : 0.f;
}

// ---------------- conv + silu (+ x->bf16) ----------------
__global__ __launch_bounds__(256) void conv_silu(
    const float* __restrict__ x,
    const float* __restrict__ qw, const float* __restrict__ qb,
    const float* __restrict__ kw, const float* __restrict__ kb,
    const float* __restrict__ vw, const float* __restrict__ vb,
    unsigned short* __restrict__ qx, unsigned short* __restrict__ kx,
    unsigned short* __restrict__ vx, unsigned short* __restrict__ xb) {
  const int n = blockIdx.x;
  const int t = n & (TT - 1);
  const int d0 = threadIdx.x * 4;
  const size_t base = (size_t)n * DD + d0;
  f32x4 zero = {0.f, 0.f, 0.f, 0.f};
  f32x4 x0 = *(const f32x4*)(x + base);
  f32x4 xm1 = (t >= 1) ? *(const f32x4*)(x + base - DD) : zero;
  f32x4 xm2 = (t >= 2) ? *(const f32x4*)(x + base - 2 * DD) : zero;
  f32x4 xm3 = (t >= 3) ? *(const f32x4*)(x + base - 3 * DD) : zero;
  float sq[4], sk[4], sv[4];
#pragma unroll
  for (int e = 0; e < 4; ++e) {
    const int d = d0 + e;
    const f32x4 wq = *(const f32x4*)(qw + (size_t)d * 4);
    const f32x4 wk = *(const f32x4*)(kw + (size_t)d * 4);
    const f32x4 wv = *(const f32x4*)(vw + (size_t)d * 4);
    float aq = wq[0] * xm3[e] + wq[1] * xm2[e] + wq[2] * xm1[e] + wq[3] * x0[e] + qb[d];
    float ak = wk[0] * xm3[e] + wk[1] * xm2[e] + wk[2] * xm1[e] + wk[3] * x0[e] + kb[d];
    float av = wv[0] * xm3[e] + wv[1] * xm2[e] + wv[2] * xm1[e] + wv[3] * x0[e] + vb[d];
    sq[e] = siluf(aq); sk[e] = siluf(ak); sv[e] = siluf(av);
  }
  u32x2 o;
  o[0] = pk2(sq[0], sq[1]); o[1] = pk2(sq[2], sq[3]); *(u32x2*)(qx + base) = o;
  o[0] = pk2(sk[0], sk[1]); o[1] = pk2(sk[2], sk[3]); *(u32x2*)(kx + base) = o;
  o[0] = pk2(sv[0], sv[1]); o[1] = pk2(sv[2], sv[3]); *(u32x2*)(vx + base) = o;
  o[0] = pk2(x0[0], x0[1]); o[1] = pk2(x0[2], x0[3]); *(u32x2*)(xb + base) = o;
}

// ---------------- bf16 MFMA GEMM (A [M,K] row-major, Bt = B^T [N,K] row-major) ----------------
template <int ACT>  // 0 none, 1 sigmoid
__global__ __launch_bounds__(256) void gemm_bt(
    const unsigned short* __restrict__ A, const unsigned short* __restrict__ Bt,
    const float* __restrict__ bias, float* __restrict__ C,
    int M, int N, int K, int ldc, int nstore) {
  __shared__ unsigned short lsA[128 * 32];
  __shared__ unsigned short lsB[128 * 32];
  const int tid = threadIdx.x;
  const int wid = tid >> 6, lane = tid & 63;
  const int wr = wid >> 1, wc = wid & 1;
  const int m0 = blockIdx.x * 128, n0 = blockIdx.y * 128;
  f32x4 acc[4][4] = {};
  const int nk = K >> 5;
  const int r0 = wid * 32 + (lane >> 2);
  const int cb = (lane & 3) * 16;
  char* lA = (char*)lsA;
  char* lB = (char*)lsB;
  const size_t rowb = (size_t)K * 2;

  for (int kt = 0; kt < nk; ++kt) {
    const char* gA = (const char*)(A + (size_t)(m0 + r0) * K) + kt * 64 + cb;
    const char* gB = (const char*)(Bt + (size_t)(n0 + r0) * K) + kt * 64 + cb;
    GLL(gA, lA + (wid * 32) * 64, 16);
    GLL(gA + 16 * rowb, lA + (wid * 32 + 16) * 64, 16);
    GLL(gB, lB + (wid * 32) * 64, 16);
    GLL(gB + 16 * rowb, lB + (wid * 32 + 16) * 64, 16);
    __syncthreads();
    bf16x8 af[4], bfr[4];
#pragma unroll
    for (int f = 0; f < 4; ++f)
      af[f] = *(const bf16x8*)(lA + (wr * 64 + f * 16 + (lane & 15)) * 64 + (lane >> 4) * 16);
#pragma unroll
    for (int f = 0; f < 4; ++f)
      bfr[f] = *(const bf16x8*)(lB + (wc * 64 + f * 16 + (lane & 15)) * 64 + (lane >> 4) * 16);
#pragma unroll
    for (int i = 0; i < 4; ++i)
#pragma unroll
      for (int j = 0; j < 4; ++j)
        acc[i][j] = __builtin_amdgcn_mfma_f32_16x16x32_bf16(af[i], bfr[j], acc[i][j], 0, 0, 0);
    __syncthreads();
  }
#pragma unroll
  for (int i = 0; i < 4; ++i) {
    const int gr0 = m0 + wr * 64 + i * 16 + (lane >> 4) * 4;
#pragma unroll
    for (int j = 0; j < 4; ++j) {
      const int gc = n0 + wc * 64 + j * 16 + (lane & 15);
      if (gc < nstore) {
        const float bv = bias[gc];
#pragma unroll
        for (int r = 0; r < 4; ++r) {
          float v = acc[i][j][r] + bv;
          if (ACT == 1) v = sigmf(v);
          C[(size_t)(gr0 + r) * ldc + gc] = v;
        }
      }
    }
  }
}

// ---------------- row-segment l2 norm (in-place, per 64-wide head segment) ----------------
__global__ __launch_bounds__(256) void l2norm_rows(float* __restrict__ Q) {
  const int tid = threadIdx.x;
  const int row = blockIdx.x * 4 + (tid >> 6);
  const int lane = tid & 63;
  float* p = Q + (size_t)row * DD + lane * 16;
  f32x4 v[4];
  float ss = 0.f;
#pragma unroll
  for (int u = 0; u < 4; ++u) {
    v[u] = *(const f32x4*)(p + u * 4);
#pragma unroll
    for (int e = 0; e < 4; ++e) ss = fmaf(v[u][e], v[u][e], ss);
  }
  ss += __shfl_xor(ss, 1);
  ss += __shfl_xor(ss, 2);
  const float rs = 1.f / sqrtf(fmaxf(ss, 1e-6f));
#pragma unroll
  for (int u = 0; u < 4; ++u) {
    f32x4 o;
#pragma unroll
    for (int e = 0; e < 4; ++e) o[e] = v[u][e] * rs;
    *(f32x4*)(p + u * 4) = o;
  }
}

// ---------------- prep: silu->bf16 for ad/gd, sigmoid beta -> [BH][T] ----------------
__global__ void prep(const float* __restrict__ s1, unsigned short* __restrict__ ad,
                     unsigned short* __restrict__ gd, float* __restrict__ betaT) {
  const int n = blockIdx.x, t = threadIdx.x;  // block 128
  float v = s1[(size_t)n * 256 + t];
  if (t < 64) ad[(size_t)n * 64 + t] = f2bf(siluf(v));
  else gd[(size_t)n * 64 + (t - 64)] = f2bf(siluf(v));
  if (t < 16) {
    float b = s1[(size_t)n * 256 + 128 + t];
    int bb = n >> 11, tt = n & (TT - 1);
    betaT[((size_t)(bb * HH + t)) * TT + tt] = sigmf(b);
  }
}

// ---------------- the delta-rule scan ----------------
// 1 block per (b,h); 4 waves; wave w owns state rows [16w,16w+16); lane = column j.
__global__ __launch_bounds__(256) void scan_kernel(
    const float* __restrict__ Qn, const float* __restrict__ Kn,
    const float* __restrict__ V, const float* __restrict__ Alp,
    const float* __restrict__ betaT, float* __restrict__ O, float* __restrict__ Sout) {
  __shared__ float slot[PF][4][64];  // [slot][a,k,q,v][i]
  __shared__ float part_t1[4][64];
  __shared__ float part_o[4][64];
  const int bh = (int)blockIdx.x;
  const int b = bh >> 4, h = bh & 15;
  const int tid = threadIdx.x;
  const int w = tid >> 6, lane = tid & 63;
  const size_t seg = ((size_t)b * TT) * DD + h * 64;
  const float* src = (w == 0) ? Alp : (w == 1) ? Kn : (w == 2) ? Qn : V;
  src += seg + lane;
  float S[16];
#pragma unroll
  for (int i = 0; i < 16; ++i) S[i] = 0.f;

  // prologue: PF slots in flight per wave (each wave stages its own array)
  for (int t = 0; t < PF; ++t) GLL(src + (size_t)t * DD, &slot[t][w][0], 4);
  float bcur = betaT[(size_t)bh * TT];

  for (int t = 0; t < TT; ++t) {
    // own oldest gll (slot t) retired, then barrier -> all 4 arrays visible
    if (w == 0 && t > 0) asm volatile("s_waitcnt vmcnt(8) lgkmcnt(0)" ::: "memory");
    else                 asm volatile("s_waitcnt vmcnt(7) lgkmcnt(0)" ::: "memory");
    asm volatile("s_barrier" ::: "memory");

    const int s = t & (PF - 1);
    const f32x4* a4 = (const f32x4*)&slot[s][0][w * 16];
    const f32x4* k4 = (const f32x4*)&slot[s][1][w * 16];
    const f32x4* q4 = (const f32x4*)&slot[s][2][w * 16];
    const float vj = slot[s][3][lane];
    const float bnext = betaT[(size_t)bh * TT + ((t + 1 < TT) ? t + 1 : TT - 1)];

    // pass1: S = diag(a) S ; t1 = (k^T S)_j over this wave's rows
    float t1 = 0.f;
#pragma unroll
    for (int u = 0; u < 4; ++u) {
      f32x4 av = a4[u], kv = k4[u];
#pragma unroll
      for (int e = 0; e < 4; ++e) {
        float sa = av[e] * S[u * 4 + e];
        t1 = fmaf(kv[e], sa, t1);
        S[u * 4 + e] = sa;
      }
    }
    part_t1[w][lane] = t1;
    asm volatile("s_waitcnt lgkmcnt(0)" ::: "memory");
    asm volatile("s_barrier" ::: "memory");   // mid barrier (keeps vmcnt in flight)

    const float t1f = part_t1[0][lane] + part_t1[1][lane] + part_t1[2][lane] + part_t1[3][lane];
    const float delta = bcur * (vj - t1f);

    // pass2: S += k * delta ; o_j = (S^T q)_j partial
    float o = 0.f;
#pragma unroll
    for (int u = 0; u < 4; ++u) {
      f32x4 kv = k4[u], qv = q4[u];
#pragma unroll
      for (int e = 0; e < 4; ++e) {
        float s2 = fmaf(kv[e], delta, S[u * 4 + e]);
        S[u * 4 + e] = s2;
        o = fmaf(qv[e], s2, o);
      }
    }
    part_o[w][lane] = o;
    asm volatile("s_waitcnt lgkmcnt(0)" ::: "memory");
    asm volatile("s_barrier" ::: "memory");   // end barrier: slot t free, part_o visible

    // refill slot (t+PF) — everyone is done reading slot s
    {
      int tn = t + PF; if (tn > TT - 1) tn = TT - 1;
      GLL(src + (size_t)tn * DD, &slot[s][w][0], 4);
    }
    if (w == 0) {
      float of = part_o[0][lane] + part_o[1][lane] + part_o[2][lane] + part_o[3][lane];
      O[seg + (size_t)t * DD + lane] = of;
    }
    bcur = bnext;
  }
  // final state [B,H,DK,DV]
  float* sp = Sout + (size_t)bh * 4096 + (size_t)(w * 16) * 64 + lane;
#pragma unroll
  for (int i = 0; i < 16; ++i) sp[i * 64] = S[i];
}

// ---------------- headwise RMSNorm * rms_w * gate -> bf16 ----------------
__global__ __launch_bounds__(256) void rms_gate(
    const float* __restrict__ O, const float* __restrict__ rmsw,
    const float* __restrict__ gate, unsigned short* __restrict__ Og) {
  const int tid = threadIdx.x;
  const int row = blockIdx.x * 4 + (tid >> 6);
  const int lane = tid & 63;
  const int h = lane >> 2;
  const float* p = O + (size_t)row * DD + lane * 16;
  f32x4 v[4];
  float ss = 0.f;
#pragma unroll
  for (int u = 0; u < 4; ++u) {
    v[u] = *(const f32x4*)(p + u * 4);
#pragma unroll
    for (int e = 0; e < 4; ++e) ss = fmaf(v[u][e], v[u][e], ss);
  }
  ss += __shfl_xor(ss, 1);
  ss += __shfl_xor(ss, 2);
  const float rs = rsqrtf(ss * (1.f / 64.f) + 1e-6f);
  const float g = gate[row * 16 + h];
  const float* wp = rmsw + h * 64 + (lane & 3) * 16;
  unsigned ow[8];
#pragma unroll
  for (int u = 0; u < 4; ++u) {
    f32x4 wv = *(const f32x4*)(wp + u * 4);
    float a0 = v[u][0] * rs * wv[0] * g, a1 = v[u][1] * rs * wv[1] * g;
    float a2 = v[u][2] * rs * wv[2] * g, a3 = v[u][3] * rs * wv[3] * g;
    ow[u * 2] = pk2(a0, a1);
    ow[u * 2 + 1] = pk2(a2, a3);
  }
  u32x4* dst = (u32x4*)(Og + (size_t)row * DD + lane * 16);
  u32x4 o1, o2;
  o1[0] = ow[0]; o1[1] = ow[1]; o1[2] = ow[2]; o1[3] = ow[3];
  o2[0] = ow[4]; o2[1] = ow[5]; o2[2] = ow[6]; o2[3] = ow[7];
  dst[0] = o1; dst[1] = o2;
}

// ---------------- launch ----------------
extern "C" void kernel_launch(void* const* d_in, const int* in_sizes, int n_in,
                              void* d_out, int out_size, void* d_ws, size_t ws_size,
                              hipStream_t stream) {
  const float* x    = (const float*)d_in[0];
  const float* qw   = (const float*)d_in[1];
  const float* qb   = (const float*)d_in[2];
  const float* kw   = (const float*)d_in[3];
  const float* kb   = (const float*)d_in[4];
  const float* vw   = (const float*)d_in[5];
  const float* vb   = (const float*)d_in[6];
  const float* Wq   = (const float*)d_in[7];
  const float* bq   = (const float*)d_in[8];
  const float* Wk   = (const float*)d_in[9];
  const float* bk   = (const float*)d_in[10];
  const float* Wv   = (const float*)d_in[11];
  const float* bv   = (const float*)d_in[12];
  const float* Wad  = (const float*)d_in[13];
  const float* bad  = (const float*)d_in[14];
  const float* Wau  = (const float*)d_in[15];
  const float* bau  = (const float*)d_in[16];
  const float* Wbeta= (const float*)d_in[17];
  const float* bbeta= (const float*)d_in[18];
  const float* rmsw = (const float*)d_in[19];
  const float* Wgd  = (const float*)d_in[20];
  const float* bgd  = (const float*)d_in[21];
  const float* Wgu  = (const float*)d_in[22];
  const float* bgu  = (const float*)d_in[23];
  const float* Wo   = (const float*)d_in[24];
  const float* bo   = (const float*)d_in[25];

  char* ws = (char*)d_ws;
  const size_t MB = 1ull << 20;
  unsigned short* WqT   = (unsigned short*)(ws + 0 * MB);
  unsigned short* WkT   = (unsigned short*)(ws + 2 * MB);
  unsigned short* WvT   = (unsigned short*)(ws + 4 * MB);
  unsigned short* WoT   = (unsigned short*)(ws + 6 * MB);
  unsigned short* WauT  = (unsigned short*)(ws + 8 * MB);
  unsigned short* Wst1T = (unsigned short*)(ws + 8 * MB + 256 * 1024);
  unsigned short* WguT  = (unsigned short*)(ws + 8 * MB + 768 * 1024);
  float* bst1 = (float*)(ws + 8 * MB + 800 * 1024);
  float* bgup = (float*)(ws + 8 * MB + 804 * 1024);
  unsigned short* x_bf = (unsigned short*)(ws + 9 * MB);
  unsigned short* qx   = (unsigned short*)(ws + 25 * MB);
  unsigned short* kx   = (unsigned short*)(ws + 41 * MB);
  unsigned short* vx   = (unsigned short*)(ws + 57 * MB);
  float* Qn    = (float*)(ws + 73 * MB);
  float* Kn    = (float*)(ws + 105 * MB);
  float* Vv    = (float*)(ws + 137 * MB);
  float* stage1= (float*)(ws + 169 * MB);
  unsigned short* adb = (unsigned short*)(ws + 177 * MB);
  unsigned short* gdb = (unsigned short*)(ws + 178 * MB);
  float* betaT = (float*)(ws + 179 * MB);
  float* gate  = (float*)(ws + 179 * MB + 512 * 1024);
  // reuse (order-safe): alpha over x_bf+qx, O over kx+vx, Og over V
  float* alpha = (float*)(ws + 9 * MB);
  float* Obuf  = (float*)(ws + 41 * MB);
  unsigned short* Og = (unsigned short*)(ws + 137 * MB);
  float* y = (float*)d_out;
  float* Sout = y + (size_t)NR * DD;

  dim3 blk(256);
  transpose_convert<<<dim3(16, 16), blk, 0, stream>>>(Wq, WqT, 1024, 1024);
  transpose_convert<<<dim3(16, 16), blk, 0, stream>>>(Wk, WkT, 1024, 1024);
  transpose_convert<<<dim3(16, 16), blk, 0, stream>>>(Wv, WvT, 1024, 1024);
  transpose_convert<<<dim3(16, 16), blk, 0, stream>>>(Wo, WoT, 1024, 1024);
  conv_small_T<<<dim3(256), blk, 0, stream>>>(Wau, WauT, 64, 1024, 1024);
  pack_stage1_T<<<dim3(1024), blk, 0, stream>>>(Wad, Wgd, Wbeta, Wst1T);
  conv_small_T<<<dim3(32), blk, 0, stream>>>(Wgu, WguT, 64, 16, 128);
  pack_bias<<<dim3(1), blk, 0, stream>>>(bad, bgd, bbeta, bgu, bst1, bgup);

  conv_silu<<<dim3(NR), blk, 0, stream>>>(x, qw, qb, kw, kb, vw, vb, qx, kx, vx, x_bf);

  gemm_bt<0><<<dim3(64, 2), blk, 0, stream>>>(x_bf, Wst1T, bst1, stage1, NR, 256, 1024, 256, 256);
  gemm_bt<0><<<dim3(64, 8), blk, 0, stream>>>(qx, WqT, bq, Qn, NR, 1024, 1024, 1024, 1024);
  gemm_bt<0><<<dim3(64, 8), blk, 0, stream>>>(kx, WkT, bk, Kn, NR, 1024, 1024, 1024, 1024);
  gemm_bt<0><<<dim3(64, 8), blk, 0, stream>>>(vx, WvT, bv, Vv, NR, 1024, 1024, 1024, 1024);
  l2norm_rows<<<dim3(2048), blk, 0, stream>>>(Qn);
  l2norm_rows<<<dim3(2048), blk, 0, stream>>>(Kn);
  prep<<<dim3(NR), dim3(128), 0, stream>>>(stage1, adb, gdb, betaT);
  gemm_bt<1><<<dim3(64, 8), blk, 0, stream>>>(adb, WauT, bau, alpha, NR, 1024, 64, 1024, 1024);
  gemm_bt<1><<<dim3(64, 1), blk, 0, stream>>>(gdb, WguT, bgup, gate, NR, 128, 64, 16, 16);

  scan_kernel<<<dim3(64), blk, 0, stream>>>(Qn, Kn, Vv, alpha, betaT, Obuf, Sout);

  rms_gate<<<dim3(2048), blk, 0, stream>>>(Obuf, rmsw, gate, Og);
  gemm_bt<0><<<dim3(64, 8), blk, 0, stream>>>(Og, WoT, bo, y, NR, 1024, 1024, 1024, 1024);
}

// Round 2
// 1110.681 us; speedup vs baseline: 1.2727x; 1.2727x over previous
//
#include <hip/hip_runtime.h>
#include <hip/hip_bf16.h>
#include <cstdint>

#define BB 4
#define TT 2048
#define DD 1024
#define HH 16
#define NR (BB*TT)   /* 8192 rows */
#define PF 8         /* scan prefetch depth (slots) */

typedef __attribute__((ext_vector_type(8))) short bf16x8;
typedef __attribute__((ext_vector_type(4))) float f32x4;
typedef __attribute__((ext_vector_type(4))) unsigned int u32x4;
typedef __attribute__((ext_vector_type(2))) unsigned int u32x2;

// async global->LDS (dest = wave-uniform base + lane*SZ; src is per-lane)
#define GLL(g, l, SZ) __builtin_amdgcn_global_load_lds( \
    (const __attribute__((address_space(1))) void*)(uintptr_t)(const void*)(g), \
    (__attribute__((address_space(3))) void*)(uintptr_t)(void*)(l), SZ, 0, 0)

__device__ __forceinline__ unsigned short f2bf(float f) {
  unsigned u = __builtin_bit_cast(unsigned, f);
  unsigned r = 0x7FFFu + ((u >> 16) & 1u);
  return (unsigned short)((u + r) >> 16);
}
__device__ __forceinline__ unsigned pk2(float a, float b) {
  return (unsigned)f2bf(a) | ((unsigned)f2bf(b) << 16);
}
__device__ __forceinline__ float siluf(float v) { return v / (1.f + __expf(-v)); }
__device__ __forceinline__ float sigmf(float v) { return 1.f / (1.f + __expf(-v)); }

// ---------------- weight preprocessing ----------------

// W [K][N] f32 -> Wt [N][K] bf16 (tiled transpose)
__global__ __launch_bounds__(256) void transpose_convert(
    const float* __restrict__ W, unsigned short* __restrict__ Wt, int K, int N) {
  __shared__ float tile[64][65];
  const int tid = threadIdx.x;
  const int bk = blockIdx.x * 64, bn = blockIdx.y * 64;
  const int r = tid >> 2, c4 = (tid & 3) * 16;
#pragma unroll 4
  for (int e = 0; e < 16; ++e)
    tile[r][c4 + e] = W[(size_t)(bk + r) * N + bn + c4 + e];
  __syncthreads();
#pragma unroll 4
  for (int e = 0; e < 16; ++e)
    Wt[(size_t)(bn + r) * K + bk + c4 + e] = f2bf(tile[c4 + e][r]);
}

// W [K][N] f32 -> Wt [Npad][K] bf16, zero rows >= N  (small weights)
__global__ void conv_small_T(const float* __restrict__ W, unsigned short* __restrict__ Wt,
                             int K, int N, int Npad) {
  int idx = blockIdx.x * 256 + threadIdx.x;
  if (idx >= Npad * K) return;
  int n = idx / K, k = idx - n * K;
  float v = (n < N) ? W[(size_t)k * N + n] : 0.f;
  Wt[idx] = f2bf(v);
}

// concat [W_ad | W_gd | W_beta]^T -> Wt [256][1024] bf16 (pad rows 144..255 = 0)
__global__ void pack_stage1_T(const float* __restrict__ Wad, const float* __restrict__ Wgd,
                              const float* __restrict__ Wbeta, unsigned short* __restrict__ Wt) {
  int idx = blockIdx.x * 256 + threadIdx.x;  // over 256*1024
  int n = idx >> 10, k = idx & 1023;
  float v = 0.f;
  if (n < 64) v = Wad[(size_t)k * 64 + n];
  else if (n < 128) v = Wgd[(size_t)k * 64 + (n - 64)];
  else if (n < 144) v = Wbeta[(size_t)k * 16 + (n - 128)];
  Wt[idx] = f2bf(v);
}

__global__ void pack_bias(const float* __restrict__ bad, const float* __restrict__ bgd,
                          const float* __restrict__ bbeta, const float* __restrict__ bgu,
                          float* __restrict__ bst1, float* __restrict__ bgup) {
  int t = threadIdx.x;  // 256
  float v = 0.f;
  if (t < 64) v = bad[t];
  else if (t < 128) v = bgd[t - 64];
  else if (t < 144) v = bbeta[t - 128];
  bst1[t] = v;
  if (t < 128) bgup[t] = (t < 16) ? bgu[t] : 0.f;
}

// ---------------- conv + silu (+ x->bf16) ----------------
__global__ __launch_bounds__(256) void conv_silu(
    const float* __restrict__ x,
    const float* __restrict__ qw, const float* __restrict__ qb,
    const float* __restrict__ kw, const float* __restrict__ kb,
    const float* __restrict__ vw, const float* __restrict__ vb,
    unsigned short* __restrict__ qx, unsigned short* __restrict__ kx,
    unsigned short* __restrict__ vx, unsigned short* __restrict__ xb) {
  const int n = blockIdx.x;
  const int t = n & (TT - 1);
  const int d0 = threadIdx.x * 4;
  const size_t base = (size_t)n * DD + d0;
  f32x4 zero = {0.f, 0.f, 0.f, 0.f};
  f32x4 x0 = *(const f32x4*)(x + base);
  f32x4 xm1 = (t >= 1) ? *(const f32x4*)(x + base - DD) : zero;
  f32x4 xm2 = (t >= 2) ? *(const f32x4*)(x + base - 2 * DD) : zero;
  f32x4 xm3 = (t >= 3) ? *(const f32x4*)(x + base - 3 * DD) : zero;
  float sq[4], sk[4], sv[4];
#pragma unroll
  for (int e = 0; e < 4; ++e) {
    const int d = d0 + e;
    const f32x4 wq = *(const f32x4*)(qw + (size_t)d * 4);
    const f32x4 wk = *(const f32x4*)(kw + (size_t)d * 4);
    const f32x4 wv = *(const f32x4*)(vw + (size_t)d * 4);
    float aq = wq[0] * xm3[e] + wq[1] * xm2[e] + wq[2] * xm1[e] + wq[3] * x0[e] + qb[d];
    float ak = wk[0] * xm3[e] + wk[1] * xm2[e] + wk[2] * xm1[e] + wk[3] * x0[e] + kb[d];
    float av = wv[0] * xm3[e] + wv[1] * xm2[e] + wv[2] * xm1[e] + wv[3] * x0[e] + vb[d];
    sq[e] = siluf(aq); sk[e] = siluf(ak); sv[e] = siluf(av);
  }
  u32x2 o;
  o[0] = pk2(sq[0], sq[1]); o[1] = pk2(sq[2], sq[3]); *(u32x2*)(qx + base) = o;
  o[0] = pk2(sk[0], sk[1]); o[1] = pk2(sk[2], sk[3]); *(u32x2*)(kx + base) = o;
  o[0] = pk2(sv[0], sv[1]); o[1] = pk2(sv[2], sv[3]); *(u32x2*)(vx + base) = o;
  o[0] = pk2(x0[0], x0[1]); o[1] = pk2(x0[2], x0[3]); *(u32x2*)(xb + base) = o;
}

// ---------------- bf16 MFMA GEMM (A [M,K] row-major, Bt = B^T [N,K] row-major) ----------------
template <int ACT>  // 0 none, 1 sigmoid
__global__ __launch_bounds__(256) void gemm_bt(
    const unsigned short* __restrict__ A, const unsigned short* __restrict__ Bt,
    const float* __restrict__ bias, float* __restrict__ C,
    int M, int N, int K, int ldc, int nstore) {
  __shared__ unsigned short lsA[128 * 32];
  __shared__ unsigned short lsB[128 * 32];
  const int tid = threadIdx.x;
  const int wid = tid >> 6, lane = tid & 63;
  const int wr = wid >> 1, wc = wid & 1;
  const int m0 = blockIdx.x * 128, n0 = blockIdx.y * 128;
  f32x4 acc[4][4] = {};
  const int nk = K >> 5;
  const int r0 = wid * 32 + (lane >> 2);
  const int cb = (lane & 3) * 16;
  char* lA = (char*)lsA;
  char* lB = (char*)lsB;
  const size_t rowb = (size_t)K * 2;

  for (int kt = 0; kt < nk; ++kt) {
    const char* gA = (const char*)(A + (size_t)(m0 + r0) * K) + kt * 64 + cb;
    const char* gB = (const char*)(Bt + (size_t)(n0 + r0) * K) + kt * 64 + cb;
    GLL(gA, lA + (wid * 32) * 64, 16);
    GLL(gA + 16 * rowb, lA + (wid * 32 + 16) * 64, 16);
    GLL(gB, lB + (wid * 32) * 64, 16);
    GLL(gB + 16 * rowb, lB + (wid * 32 + 16) * 64, 16);
    __syncthreads();
    bf16x8 af[4], bfr[4];
#pragma unroll
    for (int f = 0; f < 4; ++f)
      af[f] = *(const bf16x8*)(lA + (wr * 64 + f * 16 + (lane & 15)) * 64 + (lane >> 4) * 16);
#pragma unroll
    for (int f = 0; f < 4; ++f)
      bfr[f] = *(const bf16x8*)(lB + (wc * 64 + f * 16 + (lane & 15)) * 64 + (lane >> 4) * 16);
#pragma unroll
    for (int i = 0; i < 4; ++i)
#pragma unroll
      for (int j = 0; j < 4; ++j)
        acc[i][j] = __builtin_amdgcn_mfma_f32_16x16x32_bf16(af[i], bfr[j], acc[i][j], 0, 0, 0);
    __syncthreads();
  }
#pragma unroll
  for (int i = 0; i < 4; ++i) {
    const int gr0 = m0 + wr * 64 + i * 16 + (lane >> 4) * 4;
#pragma unroll
    for (int j = 0; j < 4; ++j) {
      const int gc = n0 + wc * 64 + j * 16 + (lane & 15);
      if (gc < nstore) {
        const float bv = bias[gc];
#pragma unroll
        for (int r = 0; r < 4; ++r) {
          float v = acc[i][j][r] + bv;
          if (ACT == 1) v = sigmf(v);
          C[(size_t)(gr0 + r) * ldc + gc] = v;
        }
      }
    }
  }
}

// ---------------- row-segment l2 norm (in-place, per 64-wide head segment) ----------------
__global__ __launch_bounds__(256) void l2norm_rows(float* __restrict__ Q) {
  const int tid = threadIdx.x;
  const int row = blockIdx.x * 4 + (tid >> 6);
  const int lane = tid & 63;
  float* p = Q + (size_t)row * DD + lane * 16;
  f32x4 v[4];
  float ss = 0.f;
#pragma unroll
  for (int u = 0; u < 4; ++u) {
    v[u] = *(const f32x4*)(p + u * 4);
#pragma unroll
    for (int e = 0; e < 4; ++e) ss = fmaf(v[u][e], v[u][e], ss);
  }
  ss += __shfl_xor(ss, 1);
  ss += __shfl_xor(ss, 2);
  const float rs = 1.f / sqrtf(fmaxf(ss, 1e-6f));
#pragma unroll
  for (int u = 0; u < 4; ++u) {
    f32x4 o;
#pragma unroll
    for (int e = 0; e < 4; ++e) o[e] = v[u][e] * rs;
    *(f32x4*)(p + u * 4) = o;
  }
}

// ---------------- prep: silu->bf16 for ad/gd, sigmoid beta -> [BH][T] ----------------
__global__ void prep(const float* __restrict__ s1, unsigned short* __restrict__ ad,
                     unsigned short* __restrict__ gd, float* __restrict__ betaT) {
  const int n = blockIdx.x, t = threadIdx.x;  // block 128
  float v = s1[(size_t)n * 256 + t];
  if (t < 64) ad[(size_t)n * 64 + t] = f2bf(siluf(v));
  else gd[(size_t)n * 64 + (t - 64)] = f2bf(siluf(v));
  if (t < 16) {
    float b = s1[(size_t)n * 256 + 128 + t];
    int bb = n >> 11, tt = n & (TT - 1);
    betaT[((size_t)(bb * HH + t)) * TT + tt] = sigmf(b);
  }
}

// ---------------- the delta-rule scan ----------------
// 1 block per (b,h); 4 waves; wave w owns COLUMNS [16w,16w+16); lane = (rg,jj):
// rg=lane>>4 owns state rows [16rg,16rg+16), jj=lane&15 -> column c=16w+jj.
// Lane holds S[16] in regs. t1/o reduced with 2 intra-wave shuffles. NO barriers.
__global__ __launch_bounds__(256) void scan_kernel(
    const float* __restrict__ Qn, const float* __restrict__ Kn,
    const float* __restrict__ V, const float* __restrict__ Alp,
    const float* __restrict__ betaT, float* __restrict__ O, float* __restrict__ Sout) {
  __shared__ float lds[4][PF][320];  // per wave: PF slots x [a|k|q|v|beta] (64 each)
  const int bh = (int)blockIdx.x;
  const int b = bh >> 4, h = bh & 15;
  const int tid = threadIdx.x;
  const int w = tid >> 6, lane = tid & 63;
  const int rg = lane >> 4, jj = lane & 15;
  const int c = w * 16 + jj;
  const size_t seg = ((size_t)b * TT) * DD + h * 64;

  const float* gA = Alp + seg + lane;
  const float* gK = Kn + seg + lane;
  const float* gQ = Qn + seg + lane;
  const float* gV = V + seg + lane;
  const float* gB = betaT + (size_t)bh * TT;
  float* ldsw = &lds[w][0][0];

  // prologue: stage slots 0..PF-1 (5 GLL each; per-wave private; vmcnt-tracked)
  for (int t = 0; t < PF; ++t) {
    float* sl = ldsw + t * 320;
    GLL(gA + (size_t)t * DD, sl, 4);
    GLL(gK + (size_t)t * DD, sl + 64, 4);
    GLL(gQ + (size_t)t * DD, sl + 128, 4);
    GLL(gV + (size_t)t * DD, sl + 192, 4);
    GLL(gB + t, sl + 256, 4);
  }

  f32x4 S4[4] = {};
  asm volatile("s_waitcnt vmcnt(35)" ::: "memory");  // slot 0 retired
  f32x4 ca[4], ck[4], cq[4];
  float cv, cb;
  {
    const float* sl = ldsw;
#pragma unroll
    for (int u = 0; u < 4; ++u) {
      ca[u] = *(const f32x4*)(sl + rg * 16 + u * 4);
      ck[u] = *(const f32x4*)(sl + 64 + rg * 16 + u * 4);
      cq[u] = *(const f32x4*)(sl + 128 + rg * 16 + u * 4);
    }
    cv = sl[192 + c];
    cb = sl[256];
  }

  float* op = O + seg + c;

#pragma unroll 2
  for (int t = 0; t < TT; ++t) {
    // retire exactly through slot t+1's 5 GLLs (exact count: 6*(PF-2)-?; see notes)
    asm volatile("s_waitcnt vmcnt(30)" ::: "memory");
    const int sn = (t + 1) & (PF - 1);
    const float* sl = ldsw + sn * 320;
    f32x4 na[4], nk[4], nq[4];
    float nv, nb;
#pragma unroll
    for (int u = 0; u < 4; ++u) {
      na[u] = *(const f32x4*)(sl + rg * 16 + u * 4);
      nk[u] = *(const f32x4*)(sl + 64 + rg * 16 + u * 4);
      nq[u] = *(const f32x4*)(sl + 128 + rg * 16 + u * 4);
    }
    nv = sl[192 + c];
    nb = sl[256];

    // pass1: S = diag(a)S ; t1 = (k^T S)_c partial over this lane's 16 rows
    f32x4 t1v = {};
#pragma unroll
    for (int u = 0; u < 4; ++u) {
      S4[u] *= ca[u];
      t1v += ck[u] * S4[u];
    }
    float t1 = (t1v[0] + t1v[1]) + (t1v[2] + t1v[3]);
    t1 += __shfl_xor(t1, 16);
    t1 += __shfl_xor(t1, 32);
    const float dl = cb * (cv - t1);
    const f32x4 dv = {dl, dl, dl, dl};

    // pass2: S += k*delta ; o = (S^T q)_c partial
    f32x4 ov = {};
#pragma unroll
    for (int u = 0; u < 4; ++u) {
      S4[u] += ck[u] * dv;
      ov += cq[u] * S4[u];
    }
    float o = (ov[0] + ov[1]) + (ov[2] + ov[3]);
    o += __shfl_xor(o, 16);
    o += __shfl_xor(o, 32);
    if (lane < 16) op[(size_t)t * DD] = o;

    // refill slot (t&7) with step t+PF (clamped)
    {
      int tn = t + PF; if (tn > TT - 1) tn = TT - 1;
      float* rs = ldsw + (t & (PF - 1)) * 320;
      GLL(gA + (size_t)tn * DD, rs, 4);
      GLL(gK + (size_t)tn * DD, rs + 64, 4);
      GLL(gQ + (size_t)tn * DD, rs + 128, 4);
      GLL(gV + (size_t)tn * DD, rs + 192, 4);
      GLL(gB + tn, rs + 256, 4);
    }
#pragma unroll
    for (int u = 0; u < 4; ++u) { ca[u] = na[u]; ck[u] = nk[u]; cq[u] = nq[u]; }
    cv = nv; cb = nb;
  }

  // final state [B,H,DK,DV]
  float* sp = Sout + (size_t)bh * 4096 + (size_t)rg * 16 * 64 + c;
#pragma unroll
  for (int u = 0; u < 4; ++u)
#pragma unroll
    for (int e = 0; e < 4; ++e)
      sp[(size_t)(u * 4 + e) * 64] = S4[u][e];
}

// ---------------- headwise RMSNorm * rms_w * gate -> bf16 ----------------
__global__ __launch_bounds__(256) void rms_gate(
    const float* __restrict__ O, const float* __restrict__ rmsw,
    const float* __restrict__ gate, unsigned short* __restrict__ Og) {
  const int tid = threadIdx.x;
  const int row = blockIdx.x * 4 + (tid >> 6);
  const int lane = tid & 63;
  const int h = lane >> 2;
  const float* p = O + (size_t)row * DD + lane * 16;
  f32x4 v[4];
  float ss = 0.f;
#pragma unroll
  for (int u = 0; u < 4; ++u) {
    v[u] = *(const f32x4*)(p + u * 4);
#pragma unroll
    for (int e = 0; e < 4; ++e) ss = fmaf(v[u][e], v[u][e], ss);
  }
  ss += __shfl_xor(ss, 1);
  ss += __shfl_xor(ss, 2);
  const float rs = rsqrtf(ss * (1.f / 64.f) + 1e-6f);
  const float g = gate[row * 16 + h];
  const float* wp = rmsw + h * 64 + (lane & 3) * 16;
  unsigned ow[8];
#pragma unroll
  for (int u = 0; u < 4; ++u) {
    f32x4 wv = *(const f32x4*)(wp + u * 4);
    float a0 = v[u][0] * rs * wv[0] * g, a1 = v[u][1] * rs * wv[1] * g;
    float a2 = v[u][2] * rs * wv[2] * g, a3 = v[u][3] * rs * wv[3] * g;
    ow[u * 2] = pk2(a0, a1);
    ow[u * 2 + 1] = pk2(a2, a3);
  }
  u32x4* dst = (u32x4*)(Og + (size_t)row * DD + lane * 16);
  u32x4 o1, o2;
  o1[0] = ow[0]; o1[1] = ow[1]; o1[2] = ow[2]; o1[3] = ow[3];
  o2[0] = ow[4]; o2[1] = ow[5]; o2[2] = ow[6]; o2[3] = ow[7];
  dst[0] = o1; dst[1] = o2;
}

// ---------------- launch ----------------
extern "C" void kernel_launch(void* const* d_in, const int* in_sizes, int n_in,
                              void* d_out, int out_size, void* d_ws, size_t ws_size,
                              hipStream_t stream) {
  const float* x    = (const float*)d_in[0];
  const float* qw   = (const float*)d_in[1];
  const float* qb   = (const float*)d_in[2];
  const float* kw   = (const float*)d_in[3];
  const float* kb   = (const float*)d_in[4];
  const float* vw   = (const float*)d_in[5];
  const float* vb   = (const float*)d_in[6];
  const float* Wq   = (const float*)d_in[7];
  const float* bq   = (const float*)d_in[8];
  const float* Wk   = (const float*)d_in[9];
  const float* bk   = (const float*)d_in[10];
  const float* Wv   = (const float*)d_in[11];
  const float* bv   = (const float*)d_in[12];
  const float* Wad  = (const float*)d_in[13];
  const float* bad  = (const float*)d_in[14];
  const float* Wau  = (const float*)d_in[15];
  const float* bau  = (const float*)d_in[16];
  const float* Wbeta= (const float*)d_in[17];
  const float* bbeta= (const float*)d_in[18];
  const float* rmsw = (const float*)d_in[19];
  const float* Wgd  = (const float*)d_in[20];
  const float* bgd  = (const float*)d_in[21];
  const float* Wgu  = (const float*)d_in[22];
  const float* bgu  = (const float*)d_in[23];
  const float* Wo   = (const float*)d_in[24];
  const float* bo   = (const float*)d_in[25];

  char* ws = (char*)d_ws;
  const size_t MB = 1ull << 20;
  unsigned short* WqT   = (unsigned short*)(ws + 0 * MB);
  unsigned short* WkT   = (unsigned short*)(ws + 2 * MB);
  unsigned short* WvT   = (unsigned short*)(ws + 4 * MB);
  unsigned short* WoT   = (unsigned short*)(ws + 6 * MB);
  unsigned short* WauT  = (unsigned short*)(ws + 8 * MB);
  unsigned short* Wst1T = (unsigned short*)(ws + 8 * MB + 256 * 1024);
  unsigned short* WguT  = (unsigned short*)(ws + 8 * MB + 768 * 1024);
  float* bst1 = (float*)(ws + 8 * MB + 800 * 1024);
  float* bgup = (float*)(ws + 8 * MB + 804 * 1024);
  unsigned short* x_bf = (unsigned short*)(ws + 9 * MB);
  unsigned short* qx   = (unsigned short*)(ws + 25 * MB);
  unsigned short* kx   = (unsigned short*)(ws + 41 * MB);
  unsigned short* vx   = (unsigned short*)(ws + 57 * MB);
  float* Qn    = (float*)(ws + 73 * MB);
  float* Kn    = (float*)(ws + 105 * MB);
  float* Vv    = (float*)(ws + 137 * MB);
  float* stage1= (float*)(ws + 169 * MB);
  unsigned short* adb = (unsigned short*)(ws + 177 * MB);
  unsigned short* gdb = (unsigned short*)(ws + 178 * MB);
  float* betaT = (float*)(ws + 179 * MB);
  float* gate  = (float*)(ws + 179 * MB + 512 * 1024);
  // reuse (order-safe): alpha over x_bf+qx, O over kx+vx, Og over V
  float* alpha = (float*)(ws + 9 * MB);
  float* Obuf  = (float*)(ws + 41 * MB);
  unsigned short* Og = (unsigned short*)(ws + 137 * MB);
  float* y = (float*)d_out;
  float* Sout = y + (size_t)NR * DD;

  dim3 blk(256);
  transpose_convert<<<dim3(16, 16), blk, 0, stream>>>(Wq, WqT, 1024, 1024);
  transpose_convert<<<dim3(16, 16), blk, 0, stream>>>(Wk, WkT, 1024, 1024);
  transpose_convert<<<dim3(16, 16), blk, 0, stream>>>(Wv, WvT, 1024, 1024);
  transpose_convert<<<dim3(16, 16), blk, 0, stream>>>(Wo, WoT, 1024, 1024);
  conv_small_T<<<dim3(256), blk, 0, stream>>>(Wau, WauT, 64, 1024, 1024);
  pack_stage1_T<<<dim3(1024), blk, 0, stream>>>(Wad, Wgd, Wbeta, Wst1T);
  conv_small_T<<<dim3(32), blk, 0, stream>>>(Wgu, WguT, 64, 16, 128);
  pack_bias<<<dim3(1), blk, 0, stream>>>(bad, bgd, bbeta, bgu, bst1, bgup);

  conv_silu<<<dim3(NR), blk, 0, stream>>>(x, qw, qb, kw, kb, vw, vb, qx, kx, vx, x_bf);

  gemm_bt<0><<<dim3(64, 2), blk, 0, stream>>>(x_bf, Wst1T, bst1, stage1, NR, 256, 1024, 256, 256);
  gemm_bt<0><<<dim3(64, 8), blk, 0, stream>>>(qx, WqT, bq, Qn, NR, 1024, 1024, 1024, 1024);
  gemm_bt<0><<<dim3(64, 8), blk, 0, stream>>>(kx, WkT, bk, Kn, NR, 1024, 1024, 1024, 1024);
  gemm_bt<0><<<dim3(64, 8), blk, 0, stream>>>(vx, WvT, bv, Vv, NR, 1024, 1024, 1024, 1024);
  l2norm_rows<<<dim3(2048), blk, 0, stream>>>(Qn);
  l2norm_rows<<<dim3(2048), blk, 0, stream>>>(Kn);
  prep<<<dim3(NR), dim3(128), 0, stream>>>(stage1, adb, gdb, betaT);
  gemm_bt<1><<<dim3(64, 8), blk, 0, stream>>>(adb, WauT, bau, alpha, NR, 1024, 64, 1024, 1024);
  gemm_bt<1><<<dim3(64, 1), blk, 0, stream>>>(gdb, WguT, bgup, gate, NR, 128, 64, 16, 16);

  scan_kernel<<<dim3(64), blk, 0, stream>>>(Qn, Kn, Vv, alpha, betaT, Obuf, Sout);

  rms_gate<<<dim3(2048), blk, 0, stream>>>(Obuf, rmsw, gate, Og);
  gemm_bt<0><<<dim3(64, 8), blk, 0, stream>>>(Og, WoT, bo, y, NR, 1024, 1024, 1024, 1024);
}